// Round 3
// baseline (246.580 us; speedup 1.0000x reference)
//
#include <hip/hip_runtime.h>
#include <stdint.h>

typedef float f32x4 __attribute__((ext_vector_type(4)));
typedef short bf16x8 __attribute__((ext_vector_type(8)));
typedef unsigned short ushort8 __attribute__((ext_vector_type(8)));

__device__ __forceinline__ unsigned short f2bf(float x) {
  union { float f; uint32_t u; } c; c.f = x;
  return (unsigned short)((c.u + 0x8000u) >> 16);
}
__device__ __forceinline__ float bf2f(unsigned short u) {
  union { uint32_t u; float f; } c; c.u = ((uint32_t)u) << 16;
  return c.f;
}

// ---------------- prep: W_enc f32 -> bf16 swizzled tiles [nt(4)][kt(32)][256][32] ----------------
__global__ void prep_w3_k(const float* __restrict__ W, unsigned short* __restrict__ Wt) {
  int t = blockIdx.x * 256 + threadIdx.x;      // 131072
  int d  = t >> 7;                              // 0..1023 (output dim)
  int c0 = (t & 127) << 3;                      // e col block
  const float* src = W + ((size_t)d << 10) + c0;
  f32x4 f0 = *(const f32x4*)src;
  f32x4 f1 = *(const f32x4*)(src + 4);
  ushort8 u;
  u[0]=f2bf(f0[0]); u[1]=f2bf(f0[1]); u[2]=f2bf(f0[2]); u[3]=f2bf(f0[3]);
  u[4]=f2bf(f1[0]); u[5]=f2bf(f1[1]); u[6]=f2bf(f1[2]); u[7]=f2bf(f1[3]);
  int nt = d >> 8, rr = d & 255;
  int kt = c0 >> 5;
  int q  = ((c0 & 31) >> 3) ^ ((rr >> 1) & 3);   // swizzled 16B block
  *(ushort8*)(Wt + (((size_t)nt) << 18) + kt * 8192 + rr * 32 + q * 8) = u;
}

// ---------------- prep: dh = dec_hidden @ W_dec^T ----------------
__global__ void prep_dh_k(const float* __restrict__ dec, const float* __restrict__ Wd,
                          float* __restrict__ dh) {
  __shared__ float sdec[1024];
  int b = blockIdx.x >> 2;
  for (int i = threadIdx.x; i < 1024; i += 256) sdec[i] = dec[(b << 10) + i];
  __syncthreads();
  int d = ((blockIdx.x & 3) << 8) + threadIdx.x;
  const float* wr = Wd + ((size_t)d << 10);
  float a = 0.f;
  for (int k = 0; k < 1024; k += 4) {
    f32x4 wv = *(const f32x4*)(wr + k);
    f32x4 xv = *(const f32x4*)(&sdec[k]);
    a += wv[0]*xv[0] + wv[1]*xv[1] + wv[2]*xv[2] + wv[3]*xv[3];
  }
  dh[(b << 10) + d] = a;
}

// ---------------- compaction ----------------
__global__ void compact_k(const int* __restrict__ mask, int* __restrict__ rows,
                          int* __restrict__ cnt, float* __restrict__ wout) {
  int b = blockIdx.x, tid = threadIdx.x;
  int lane = tid & 63, wv = tid >> 6;
  int mloc[8]; int c = 0;
  #pragma unroll
  for (int ii = 0; ii < 8; ++ii) {
    int s = tid * 8 + ii;
    int m = mask[(b << 11) + s];
    mloc[ii] = m; c += m;
    wout[(b << 11) + s] = 0.f;
  }
  int inc = c;
  #pragma unroll
  for (int off = 1; off < 64; off <<= 1) {
    int nn = __shfl_up(inc, off);
    if (lane >= off) inc += nn;
  }
  __shared__ int wsum[4];
  if (lane == 63) wsum[wv] = inc;
  __syncthreads();
  int base = 0;
  for (int w = 0; w < wv; ++w) base += wsum[w];
  int idx = base + inc - c;
  #pragma unroll
  for (int ii = 0; ii < 8; ++ii) {
    if (mloc[ii]) { rows[(b << 11) + idx] = tid * 8 + ii; ++idx; }
  }
  if (tid == 0) cnt[b] = wsum[0] + wsum[1] + wsum[2] + wsum[3];
}

// ---------------- pack: unmasked enc rows -> bf16 swizzled tiles [b][mt(8)][kt(32)][256][32] ----------------
__global__ void pack3_k(const float* __restrict__ enc, const int* __restrict__ rows,
                        const int* __restrict__ cnt, unsigned short* __restrict__ encP) {
  int b = blockIdx.x >> 3, mt = blockIdx.x & 7;
  int n = cnt[b];
  if (mt * 256 >= n) return;
  __shared__ int sr[256];
  if (threadIdx.x < 256) {
    int i = mt * 256 + threadIdx.x; if (i >= n) i = n - 1;
    sr[threadIdx.x] = rows[(b << 11) + i];
  }
  __syncthreads();
  unsigned short* dst = encP + (((size_t)(b * 8 + mt)) << 18);
  for (int it = 0; it < 128; ++it) {
    int idx = it * 256 + threadIdx.x;    // 0..32767
    int r   = idx >> 7;                  // 0..255
    int c0  = (idx & 127) << 3;
    const float* src = enc + (((size_t)(b << 11) + sr[r]) << 10) + c0;
    f32x4 f0 = *(const f32x4*)src;
    f32x4 f1 = *(const f32x4*)(src + 4);
    ushort8 u;
    u[0]=f2bf(f0[0]); u[1]=f2bf(f0[1]); u[2]=f2bf(f0[2]); u[3]=f2bf(f0[3]);
    u[4]=f2bf(f1[0]); u[5]=f2bf(f1[1]); u[6]=f2bf(f1[2]); u[7]=f2bf(f1[3]);
    int kt = c0 >> 5;
    int q  = ((c0 & 31) >> 3) ^ ((r >> 1) & 3);
    *(ushort8*)(dst + kt * 8192 + r * 32 + q * 8) = u;
  }
}

// ---------------- main fused GEMM: 256x256 tile, BK=32, 4-slot ring, counted vmcnt ----------------
#define BAR() __builtin_amdgcn_s_barrier()
#define SBAR() __builtin_amdgcn_sched_barrier(0)

struct KtCtx {
  const unsigned short* aT;
  const unsigned short* bT;
  unsigned short* AS;
  unsigned short* BS;
  int so;     // per-thread src offset (elems)
  int ldso;   // wave-uniform LDS offset (elems)
};

__device__ __forceinline__ void stage_chunk(const unsigned short* gbase, unsigned short* lbase) {
  __builtin_amdgcn_global_load_lds((const __attribute__((address_space(1))) void*)(const void*)gbase,
                                   (__attribute__((address_space(3))) void*)(void*)lbase, 16, 0, 0);
}
__device__ __forceinline__ void stageA(const KtCtx& c, int kt, int half) {
  stage_chunk(c.aT + (((size_t)kt) << 13) + (half << 12) + c.so,
              c.AS + ((kt & 3) << 13) + (half << 12) + c.ldso);
}
__device__ __forceinline__ void stageB(const KtCtx& c, int kt, int half) {
  stage_chunk(c.bT + (((size_t)kt) << 13) + (half << 12) + c.so,
              c.BS + ((kt & 3) << 13) + (half << 12) + c.ldso);
}

template<int FN, bool S0, bool S1>
__device__ __forceinline__ void ktile_body(const KtCtx& c, int kt,
                                           const int* offA, const int* offB,
                                           f32x4 (&acc)[8][4]) {
  const unsigned short* as = c.AS + ((kt & 3) << 13);
  const unsigned short* bs = c.BS + ((kt & 3) << 13);
  bf16x8 a0[4], bb[4];
  // ---- phase 0 ----
  #pragma unroll
  for (int i = 0; i < 4; ++i) a0[i] = *(const bf16x8*)(as + offA[i]);
  #pragma unroll
  for (int j = 0; j < 4; ++j) bb[j] = *(const bf16x8*)(bs + offB[j]);
  if constexpr (S0) { stageB(c, kt + 2, 0); stageB(c, kt + 2, 1); }
  BAR();
  __builtin_amdgcn_s_setprio(1);
  #pragma unroll
  for (int i = 0; i < 4; ++i)
    #pragma unroll
    for (int j = 0; j < 4; ++j)
      acc[i][j] = __builtin_amdgcn_mfma_f32_16x16x32_bf16(a0[i], bb[j], acc[i][j], 0, 0, 0);
  __builtin_amdgcn_s_setprio(0);
  BAR();
  // ---- phase 1 ----
  bf16x8 a1[4];
  #pragma unroll
  for (int i = 0; i < 4; ++i) a1[i] = *(const bf16x8*)(as + offA[4 + i]);
  if constexpr (S1) { stageA(c, kt + 3, 0); stageA(c, kt + 3, 1); }
  BAR();
  __builtin_amdgcn_s_setprio(1);
  #pragma unroll
  for (int i = 0; i < 4; ++i)
    #pragma unroll
    for (int j = 0; j < 4; ++j)
      acc[4 + i][j] = __builtin_amdgcn_mfma_f32_16x16x32_bf16(a1[i], bb[j], acc[4 + i][j], 0, 0, 0);
  __builtin_amdgcn_s_setprio(0);
  // ---- K-tile boundary fence ----
  SBAR();
  if constexpr (FN == 6)      asm volatile("s_waitcnt vmcnt(6)" ::: "memory");
  else if constexpr (FN == 4) asm volatile("s_waitcnt vmcnt(4)" ::: "memory");
  else if constexpr (FN == 0) asm volatile("s_waitcnt vmcnt(0)" ::: "memory");
  BAR();
  SBAR();
}

__global__ __launch_bounds__(512, 2) void score3_k(
    const unsigned short* __restrict__ encP, const unsigned short* __restrict__ Wt,
    const float* __restrict__ dh, const float* __restrict__ v,
    const int* __restrict__ cnt, float* __restrict__ pscores)
{
  // XCD-contiguous bijective swizzle (1024 blocks, 8 XCDs)
  int L  = (blockIdx.x & 7) * 128 + (blockIdx.x >> 3);
  int b  = L >> 5, mt = (L >> 2) & 7, nt = L & 3;
  int n  = cnt[b];
  if (mt * 256 >= n) return;

  __shared__ __align__(16) unsigned short SMEM[65536];   // 128 KB: AS[4][8192] + BS[4][8192]
  unsigned short* AS = SMEM;
  unsigned short* BS = SMEM + 32768;

  int tid  = threadIdx.x;
  int lane = tid & 63;
  int wv   = tid >> 6;
  int wm   = wv >> 2, wn = wv & 3;      // 2 x 4 waves
  int l15  = lane & 15, l4 = lane >> 4;

  KtCtx c;
  c.aT = encP + (((size_t)(b * 8 + mt)) << 18);
  c.bT = Wt + (((size_t)nt) << 18);
  c.AS = AS; c.BS = BS;
  c.so = tid * 8;
  c.ldso = wv * 512;

  // precomputed swizzled LDS read offsets (elems)
  int offA[8], offB[4];
  #pragma unroll
  for (int mf = 0; mf < 8; ++mf) {
    int rr = wm * 128 + mf * 16 + l15;
    offA[mf] = rr * 32 + ((l4 ^ (rr >> 1)) & 3) * 8;
  }
  #pragma unroll
  for (int nf = 0; nf < 4; ++nf) {
    int rn = wn * 64 + nf * 16 + l15;
    offB[nf] = rn * 32 + ((l4 ^ (rn >> 1)) & 3) * 8;
  }

  f32x4 acc[8][4];
  #pragma unroll
  for (int i = 0; i < 8; ++i)
    #pragma unroll
    for (int j = 0; j < 4; ++j)
      acc[i][j] = (f32x4){0.f, 0.f, 0.f, 0.f};

  // prologue: chunks 0..9 (K0 full, K1 full, K2 A-halves)
  stageA(c, 0, 0); stageA(c, 0, 1); stageB(c, 0, 0); stageB(c, 0, 1);
  stageA(c, 1, 0); stageA(c, 1, 1); stageB(c, 1, 0); stageB(c, 1, 1);
  stageA(c, 2, 0); stageA(c, 2, 1);
  SBAR();
  asm volatile("s_waitcnt vmcnt(6)" ::: "memory");
  BAR();
  SBAR();

  int kt = 0;
  for (; kt < 29; ++kt) ktile_body<6, true, true>(c, kt, offA, offB, acc);
  ktile_body<4, true,  false>(c, 29, offA, offB, acc);
  ktile_body<0, false, false>(c, 30, offA, offB, acc);
  ktile_body<-1, false, false>(c, 31, offA, offB, acc);

  // epilogue: p[row] = sum_d v[d]*tanh(acc + dh[b][d]) over this nt's 256 cols
  float* sc = (float*)BS;                 // [256][4], BS is dead now
  float vv[4], dd[4];
  #pragma unroll
  for (int nf = 0; nf < 4; ++nf) {
    int dcol = nt * 256 + wn * 64 + nf * 16 + l15;
    vv[nf] = v[dcol];
    dd[nf] = dh[(b << 10) + dcol];
  }
  #pragma unroll
  for (int mf = 0; mf < 8; ++mf) {
    #pragma unroll
    for (int r = 0; r < 4; ++r) {
      float p = 0.f;
      #pragma unroll
      for (int nf = 0; nf < 4; ++nf) {
        float x = acc[mf][nf][r] + dd[nf];
        float e = __expf(2.0f * x);
        float t = 1.0f - __fdividef(2.0f, e + 1.0f);
        p += vv[nf] * t;
      }
      p += __shfl_xor(p, 1); p += __shfl_xor(p, 2);
      p += __shfl_xor(p, 4); p += __shfl_xor(p, 8);
      if (l15 == 0)
        sc[(wm * 128 + mf * 16 + (l4 << 2) + r) * 4 + wn] = p;
    }
  }
  __syncthreads();
  if (tid < 256) {
    int i = mt * 256 + tid;
    if (i < n) {
      float s = sc[tid * 4 + 0] + sc[tid * 4 + 1] + sc[tid * 4 + 2] + sc[tid * 4 + 3];
      pscores[(((size_t)nt) << 16) + (b << 11) + i] = s;
    }
  }
}

// ---------------- softmax over compacted scores (4 partials); scatter weights ----------------
__global__ void softmax3_k(const float* __restrict__ ps, const int* __restrict__ rows,
                           const int* __restrict__ cnt, float* __restrict__ wout,
                           float* __restrict__ wc) {
  int b = blockIdx.x;
  int tid = threadIdx.x;
  int n = cnt[b];
  float val[8];
  float m = -INFINITY;
  #pragma unroll
  for (int ii = 0; ii < 8; ++ii) {
    int i = tid + ii * 256;
    float s = -INFINITY;
    if (i < n) {
      s = 0.f;
      #pragma unroll
      for (int nt = 0; nt < 4; ++nt) s += ps[(((size_t)nt) << 16) + (b << 11) + i];
    }
    val[ii] = s;
    m = fmaxf(m, s);
  }
  #pragma unroll
  for (int off = 1; off < 64; off <<= 1) m = fmaxf(m, __shfl_xor(m, off));
  __shared__ float r1[4], r2[4];
  if ((tid & 63) == 0) r1[tid >> 6] = m;
  __syncthreads();
  m = fmaxf(fmaxf(r1[0], r1[1]), fmaxf(r1[2], r1[3]));
  float ssum = 0.f;
  #pragma unroll
  for (int ii = 0; ii < 8; ++ii) { val[ii] = __expf(val[ii] - m); ssum += val[ii]; }
  #pragma unroll
  for (int off = 1; off < 64; off <<= 1) ssum += __shfl_xor(ssum, off);
  if ((tid & 63) == 0) r2[tid >> 6] = ssum;
  __syncthreads();
  ssum = r2[0] + r2[1] + r2[2] + r2[3];
  float inv = 1.0f / ssum;
  #pragma unroll
  for (int ii = 0; ii < 8; ++ii) {
    int i = tid + ii * 256;
    if (i < n) {
      float w = val[ii] * inv;
      wc[(b << 11) + i] = w;
      wout[((size_t)b << 11) + rows[(b << 11) + i]] = w;
    }
  }
}

// ---------------- context partials from bf16 packed tiles ----------------
__global__ void ctx3_k(const unsigned short* __restrict__ encP, const float* __restrict__ wc,
                       const int* __restrict__ cnt, float* __restrict__ cp) {
  int b = blockIdx.x >> 3, mt = blockIdx.x & 7;
  int n = cnt[b];
  float* out = cp + (((size_t)(b * 8 + mt)) << 10);
  int tid = threadIdx.x;
  if (mt * 256 >= n) {          // dead tile: zero partial
    #pragma unroll
    for (int j = 0; j < 4; ++j) out[tid * 4 + j] = 0.f;
    return;
  }
  __shared__ float sw[256];
  __shared__ float red[128][8];
  if (tid < 256) {
    int i = mt * 256 + tid;
    sw[tid] = (i < n) ? wc[(b << 11) + i] : 0.f;
  }
  __syncthreads();
  const unsigned short* tile = encP + (((size_t)(b * 8 + mt)) << 18);
  int cb8  = tid & 127;          // logical 8-col block (cols cb8*8..+7)
  int half = tid >> 7;
  int kt = cb8 >> 2, qlog = cb8 & 3;
  float a[8];
  #pragma unroll
  for (int j = 0; j < 8; ++j) a[j] = 0.f;
  int r0 = half * 128;
  for (int rr = 0; rr < 128; ++rr) {
    int r = r0 + rr;
    float w = sw[r];
    ushort8 u = *(const ushort8*)(tile + kt * 8192 + r * 32 + ((qlog ^ (r >> 1)) & 3) * 8);
    #pragma unroll
    for (int j = 0; j < 8; ++j) a[j] += w * bf2f(u[j]);
  }
  if (half == 1) {
    #pragma unroll
    for (int j = 0; j < 8; ++j) red[cb8][j] = a[j];
  }
  __syncthreads();
  if (half == 0) {
    #pragma unroll
    for (int j = 0; j < 8; ++j) out[cb8 * 8 + j] = a[j] + red[cb8][j];
  }
}

__global__ void ctx_red3_k(const float* __restrict__ cp, float* __restrict__ out) {
  int t = blockIdx.x * 256 + threadIdx.x;   // 32768
  int b = t >> 10, e = t & 1023;
  float a = 0.f;
  #pragma unroll
  for (int mt = 0; mt < 8; ++mt) a += cp[(((size_t)(b * 8 + mt)) << 10) + e];
  out[t] = a;
}

extern "C" void kernel_launch(void* const* d_in, const int* in_sizes, int n_in,
                              void* d_out, int out_size, void* d_ws, size_t ws_size,
                              hipStream_t stream) {
  const float* dec  = (const float*)d_in[0];
  const float* enc  = (const float*)d_in[1];
  const int*   mask = (const int*)d_in[2];
  const float* Wenc = (const float*)d_in[3];
  const float* Wdec = (const float*)d_in[4];
  const float* v    = (const float*)d_in[5];
  float* out_ctx = (float*)d_out;                 // [32][1024]
  float* out_w   = (float*)d_out + 32768;         // [32][2048]

  char* ws = (char*)d_ws;
  unsigned short* Wt = (unsigned short*)ws;                       // 2 MB  bf16 W_enc swizzled tiles
  float* dh    = (float*)(ws + (2u << 20));                       // 128 KB
  int*   rows  = (int*)(ws + (2u << 20) + (128u << 10));          // 256 KB
  float* wc    = (float*)(ws + (2u << 20) + (384u << 10));        // 256 KB
  int*   cnt   = (int*)(ws + (2u << 20) + (640u << 10));          // 4 KB
  float* pscores = (float*)(ws + (3u << 20));                     // 1 MB  [4][32][2048]
  float* cp      = (float*)(ws + (5u << 20));                     // 1 MB  [32][8][1024]
  unsigned short* encP = (unsigned short*)(ws + (8ull << 20));    // 128 MB packed swizzled enc tiles

  hipLaunchKernelGGL(prep_w3_k,  dim3(512),  dim3(256), 0, stream, Wenc, Wt);
  hipLaunchKernelGGL(prep_dh_k,  dim3(128),  dim3(256), 0, stream, dec, Wdec, dh);
  hipLaunchKernelGGL(compact_k,  dim3(32),   dim3(256), 0, stream, mask, rows, cnt, out_w);
  hipLaunchKernelGGL(pack3_k,    dim3(256),  dim3(256), 0, stream, enc, rows, cnt, encP);
  hipLaunchKernelGGL(score3_k,   dim3(1024), dim3(512), 0, stream, encP, Wt, dh, v, cnt, pscores);
  hipLaunchKernelGGL(softmax3_k, dim3(32),   dim3(256), 0, stream, pscores, rows, cnt, out_w, wc);
  hipLaunchKernelGGL(ctx3_k,     dim3(256),  dim3(256), 0, stream, encP, wc, cnt, cp);
  hipLaunchKernelGGL(ctx_red3_k, dim3(128),  dim3(256), 0, stream, cp, out_ctx);
}

// Round 4
// 217.784 us; speedup vs baseline: 1.1322x; 1.1322x over previous
//
#include <hip/hip_runtime.h>
#include <stdint.h>

typedef float f32x4 __attribute__((ext_vector_type(4)));
typedef float f32x16 __attribute__((ext_vector_type(16)));
typedef short bf16x8 __attribute__((ext_vector_type(8)));
typedef unsigned short ushort8 __attribute__((ext_vector_type(8)));

__device__ __forceinline__ unsigned short f2bf(float x) {
  union { float f; uint32_t u; } c; c.f = x;
  return (unsigned short)((c.u + 0x8000u) >> 16);
}
__device__ __forceinline__ float bf2f(unsigned short u) {
  union { uint32_t u; float f; } c; c.u = ((uint32_t)u) << 16;
  return c.f;
}

// ---------------- prep: W_enc f32 -> bf16 swizzled tiles [nt(8)][kt(32)][128][32] ----------------
__global__ void prep_w4_k(const float* __restrict__ W, unsigned short* __restrict__ Wt) {
  int t = blockIdx.x * 256 + threadIdx.x;      // 131072
  int d  = t >> 7;                              // 0..1023
  int c0 = (t & 127) << 3;
  const float* src = W + ((size_t)d << 10) + c0;
  f32x4 f0 = *(const f32x4*)src;
  f32x4 f1 = *(const f32x4*)(src + 4);
  ushort8 u;
  u[0]=f2bf(f0[0]); u[1]=f2bf(f0[1]); u[2]=f2bf(f0[2]); u[3]=f2bf(f0[3]);
  u[4]=f2bf(f1[0]); u[5]=f2bf(f1[1]); u[6]=f2bf(f1[2]); u[7]=f2bf(f1[3]);
  int nt = d >> 7, r = d & 127;
  int kt = c0 >> 5;
  int q  = ((c0 & 31) >> 3) ^ ((r >> 1) & 3);
  Wt += (((size_t)(nt * 32 + kt)) << 12) + r * 32 + q * 8;
  *(ushort8*)Wt = u;
}

// ---------------- prep: dh = dec_hidden @ W_dec^T ----------------
__global__ void prep_dh_k(const float* __restrict__ dec, const float* __restrict__ Wd,
                          float* __restrict__ dh) {
  __shared__ float sdec[1024];
  int b = blockIdx.x >> 2;
  for (int i = threadIdx.x; i < 1024; i += 256) sdec[i] = dec[(b << 10) + i];
  __syncthreads();
  int d = ((blockIdx.x & 3) << 8) + threadIdx.x;
  const float* wr = Wd + ((size_t)d << 10);
  float a = 0.f;
  for (int k = 0; k < 1024; k += 4) {
    f32x4 wv = *(const f32x4*)(wr + k);
    f32x4 xv = *(const f32x4*)(&sdec[k]);
    a += wv[0]*xv[0] + wv[1]*xv[1] + wv[2]*xv[2] + wv[3]*xv[3];
  }
  dh[(b << 10) + d] = a;
}

// ---------------- compaction ----------------
__global__ void compact_k(const int* __restrict__ mask, int* __restrict__ rows,
                          int* __restrict__ cnt, float* __restrict__ wout) {
  int b = blockIdx.x, tid = threadIdx.x;
  int lane = tid & 63, wv = tid >> 6;
  int mloc[8]; int c = 0;
  #pragma unroll
  for (int ii = 0; ii < 8; ++ii) {
    int s = tid * 8 + ii;
    int m = mask[(b << 11) + s];
    mloc[ii] = m; c += m;
    wout[(b << 11) + s] = 0.f;
  }
  int inc = c;
  #pragma unroll
  for (int off = 1; off < 64; off <<= 1) {
    int nn = __shfl_up(inc, off);
    if (lane >= off) inc += nn;
  }
  __shared__ int wsum[4];
  if (lane == 63) wsum[wv] = inc;
  __syncthreads();
  int base = 0;
  for (int w = 0; w < wv; ++w) base += wsum[w];
  int idx = base + inc - c;
  #pragma unroll
  for (int ii = 0; ii < 8; ++ii) {
    if (mloc[ii]) { rows[(b << 11) + idx] = tid * 8 + ii; ++idx; }
  }
  if (tid == 0) cnt[b] = wsum[0] + wsum[1] + wsum[2] + wsum[3];
}

// ---------------- pack: unmasked enc rows -> bf16 swizzled tiles [b][mt(16)][kt(32)][128][32] ----------------
__global__ void pack4_k(const float* __restrict__ enc, const int* __restrict__ rows,
                        const int* __restrict__ cnt, unsigned short* __restrict__ encP) {
  int b = blockIdx.x >> 4, mt = blockIdx.x & 15;
  int n = cnt[b];
  if (mt * 128 >= n) return;
  __shared__ int sr[128];
  if (threadIdx.x < 128) {
    int i = mt * 128 + threadIdx.x; if (i >= n) i = n - 1;
    sr[threadIdx.x] = rows[(b << 11) + i];
  }
  __syncthreads();
  unsigned short* dst = encP + (((size_t)(b * 16 + mt)) << 17);
  for (int it = 0; it < 64; ++it) {
    int idx = it * 256 + threadIdx.x;    // 0..16383
    int r   = idx >> 7;                  // 0..127
    int c0  = (idx & 127) << 3;
    const float* src = enc + (((size_t)(b << 11) + sr[r]) << 10) + c0;
    f32x4 f0 = *(const f32x4*)src;
    f32x4 f1 = *(const f32x4*)(src + 4);
    ushort8 u;
    u[0]=f2bf(f0[0]); u[1]=f2bf(f0[1]); u[2]=f2bf(f0[2]); u[3]=f2bf(f0[3]);
    u[4]=f2bf(f1[0]); u[5]=f2bf(f1[1]); u[6]=f2bf(f1[2]); u[7]=f2bf(f1[3]);
    int kt = c0 >> 5;
    int q  = ((c0 & 31) >> 3) ^ ((r >> 1) & 3);
    *(ushort8*)(dst + (kt << 12) + r * 32 + q * 8) = u;
  }
}

// ---------------- main fused GEMM: 128x128 tile, 32x32x16 MFMA, 2-slot dbuf ----------------
__global__ __launch_bounds__(256, 3) void score4_k(
    const unsigned short* __restrict__ encP, const unsigned short* __restrict__ Wt,
    const float* __restrict__ dh, const float* __restrict__ v,
    const int* __restrict__ cnt, float* __restrict__ pscores)
{
  // XCD swizzle: 8 consecutive same-XCD ids share one A-tile (sweep nt fastest)
  int L  = (blockIdx.x & 7) * 512 + (blockIdx.x >> 3);   // bijective, 4096 = 8*512
  int b  = L >> 7, mt = (L >> 3) & 15, nt = L & 7;
  int n  = cnt[b];
  if (mt * 128 >= n) return;

  __shared__ __align__(16) unsigned short AS[2][4096];
  __shared__ __align__(16) unsigned short BS[2][4096];
  __shared__ float sc[128][2];

  int tid  = threadIdx.x;
  int lane = tid & 63;
  int wv   = tid >> 6;
  int wm = wv >> 1, wn = wv & 1;        // 2 x 2 waves, wave tile 64x64
  int l31 = lane & 31, l5 = lane >> 5;

  const unsigned short* aT = encP + (((size_t)(b * 16 + mt)) << 17);
  const unsigned short* bT = Wt + (((size_t)nt) << 17);

  // swizzled LDS read offsets (elems): frag (x, ki): row xr, 16B-block (ki*2+l5)^((xr>>1)&3)
  int offA[2][2], offB[2][2];
  #pragma unroll
  for (int mf = 0; mf < 2; ++mf) {
    int r = wm * 64 + mf * 32 + l31;
    #pragma unroll
    for (int ki = 0; ki < 2; ++ki)
      offA[mf][ki] = r * 32 + (((ki * 2 + l5) ^ ((r >> 1) & 3)) << 3);
  }
  #pragma unroll
  for (int nf = 0; nf < 2; ++nf) {
    int r = wn * 64 + nf * 32 + l31;
    #pragma unroll
    for (int ki = 0; ki < 2; ++ki)
      offB[nf][ki] = r * 32 + (((ki * 2 + l5) ^ ((r >> 1) & 3)) << 3);
  }

  f32x16 acc[2][2];
  #pragma unroll
  for (int i = 0; i < 2; ++i)
    #pragma unroll
    for (int j = 0; j < 2; ++j)
      #pragma unroll
      for (int e = 0; e < 16; ++e)
        acc[i][j][e] = 0.f;

  auto stage = [&](int slot, int kt) {
    #pragma unroll
    for (int j = 0; j < 2; ++j) {
      int chunk = wv * 2 + j;
      __builtin_amdgcn_global_load_lds(
        (const __attribute__((address_space(1))) void*)(const void*)(aT + ((size_t)kt << 12) + chunk * 512 + lane * 8),
        (__attribute__((address_space(3))) void*)(void*)(&AS[slot][chunk * 512]), 16, 0, 0);
      __builtin_amdgcn_global_load_lds(
        (const __attribute__((address_space(1))) void*)(const void*)(bT + ((size_t)kt << 12) + chunk * 512 + lane * 8),
        (__attribute__((address_space(3))) void*)(void*)(&BS[slot][chunk * 512]), 16, 0, 0);
    }
  };

  auto compute = [&](int slot) {
    bf16x8 af[2][2], bf[2][2];
    #pragma unroll
    for (int mf = 0; mf < 2; ++mf)
      #pragma unroll
      for (int ki = 0; ki < 2; ++ki)
        af[mf][ki] = *(const bf16x8*)&AS[slot][offA[mf][ki]];
    #pragma unroll
    for (int nf = 0; nf < 2; ++nf)
      #pragma unroll
      for (int ki = 0; ki < 2; ++ki)
        bf[nf][ki] = *(const bf16x8*)&BS[slot][offB[nf][ki]];
    #pragma unroll
    for (int ki = 0; ki < 2; ++ki)
      #pragma unroll
      for (int mf = 0; mf < 2; ++mf)
        #pragma unroll
        for (int nf = 0; nf < 2; ++nf)
          acc[mf][nf] = __builtin_amdgcn_mfma_f32_32x32x16_bf16(af[mf][ki], bf[nf][ki], acc[mf][nf], 0, 0, 0);
  };

  stage(0, 0);
  __syncthreads();
  int slot = 0;
  for (int kt = 0; kt < 31; ++kt) {
    stage(slot ^ 1, kt + 1);
    compute(slot);
    __syncthreads();
    slot ^= 1;
  }
  compute(slot);

  // epilogue: p[row] = sum_d v[d]*tanh(acc + dh[b][d]); C layout: col=l31, row=(reg&3)+8*(reg>>2)+4*l5
  float vv[2], dd[2];
  #pragma unroll
  for (int nf = 0; nf < 2; ++nf) {
    int dcol = nt * 128 + wn * 64 + nf * 32 + l31;
    vv[nf] = v[dcol];
    dd[nf] = dh[(b << 10) + dcol];
  }
  #pragma unroll
  for (int mf = 0; mf < 2; ++mf) {
    #pragma unroll
    for (int reg = 0; reg < 16; ++reg) {
      float p = 0.f;
      #pragma unroll
      for (int nf = 0; nf < 2; ++nf) {
        float x = acc[mf][nf][reg] + dd[nf];
        float e = __expf(2.0f * x);                 // tanh(x) = 1 - 2/(e^{2x}+1)
        float t = 1.0f - __fdividef(2.0f, e + 1.0f);
        p += vv[nf] * t;
      }
      p += __shfl_xor(p, 1); p += __shfl_xor(p, 2); p += __shfl_xor(p, 4);
      p += __shfl_xor(p, 8); p += __shfl_xor(p, 16);
      if (l31 == 0) {
        int row = wm * 64 + mf * 32 + (reg & 3) + 8 * (reg >> 2) + 4 * l5;
        sc[row][wn] = p;
      }
    }
  }
  __syncthreads();
  if (tid < 128) {
    int i = mt * 128 + tid;
    if (i < n)
      pscores[(((size_t)nt) << 16) + (b << 11) + i] = sc[tid][0] + sc[tid][1];
  }
}

// ---------------- softmax over compacted scores (8 partials); scatter weights ----------------
__global__ void softmax4_k(const float* __restrict__ ps, const int* __restrict__ rows,
                           const int* __restrict__ cnt, float* __restrict__ wout,
                           float* __restrict__ wc) {
  int b = blockIdx.x;
  int tid = threadIdx.x;
  int n = cnt[b];
  float val[8];
  float m = -INFINITY;
  #pragma unroll
  for (int ii = 0; ii < 8; ++ii) {
    int i = tid + ii * 256;
    float s = -INFINITY;
    if (i < n) {
      s = 0.f;
      #pragma unroll
      for (int nt = 0; nt < 8; ++nt) s += ps[(((size_t)nt) << 16) + (b << 11) + i];
    }
    val[ii] = s;
    m = fmaxf(m, s);
  }
  #pragma unroll
  for (int off = 1; off < 64; off <<= 1) m = fmaxf(m, __shfl_xor(m, off));
  __shared__ float r1[4], r2[4];
  if ((tid & 63) == 0) r1[tid >> 6] = m;
  __syncthreads();
  m = fmaxf(fmaxf(r1[0], r1[1]), fmaxf(r1[2], r1[3]));
  float ssum = 0.f;
  #pragma unroll
  for (int ii = 0; ii < 8; ++ii) { val[ii] = __expf(val[ii] - m); ssum += val[ii]; }
  #pragma unroll
  for (int off = 1; off < 64; off <<= 1) ssum += __shfl_xor(ssum, off);
  if ((tid & 63) == 0) r2[tid >> 6] = ssum;
  __syncthreads();
  ssum = r2[0] + r2[1] + r2[2] + r2[3];
  float inv = 1.0f / ssum;
  #pragma unroll
  for (int ii = 0; ii < 8; ++ii) {
    int i = tid + ii * 256;
    if (i < n) {
      float w = val[ii] * inv;
      wc[(b << 11) + i] = w;
      wout[((size_t)b << 11) + rows[(b << 11) + i]] = w;
    }
  }
}

// ---------------- context partials from bf16 packed tiles [b][mt(16)] ----------------
__global__ void ctx4_k(const unsigned short* __restrict__ encP, const float* __restrict__ wc,
                       const int* __restrict__ cnt, float* __restrict__ cp) {
  int b = blockIdx.x >> 4, mt = blockIdx.x & 15;
  int n = cnt[b];
  float* out = cp + (((size_t)(b * 16 + mt)) << 10);
  int tid = threadIdx.x;
  if (mt * 128 >= n) {
    #pragma unroll
    for (int j = 0; j < 4; ++j) out[tid * 4 + j] = 0.f;
    return;
  }
  __shared__ float sw[128];
  __shared__ float red[128][8];
  if (tid < 128) {
    int i = mt * 128 + tid;
    sw[tid] = (i < n) ? wc[(b << 11) + i] : 0.f;
  }
  __syncthreads();
  const unsigned short* tile = encP + (((size_t)(b * 16 + mt)) << 17);
  int cb8  = tid & 127;          // 8-col block (cols cb8*8..+7)
  int half = tid >> 7;           // rows 0-63 / 64-127
  int kt = cb8 >> 2, q0 = cb8 & 3;
  float a[8];
  #pragma unroll
  for (int j = 0; j < 8; ++j) a[j] = 0.f;
  for (int rr = 0; rr < 64; ++rr) {
    int r = half * 64 + rr;
    float w = sw[r];
    ushort8 u = *(const ushort8*)(tile + (kt << 12) + r * 32 + ((q0 ^ ((r >> 1) & 3)) << 3));
    #pragma unroll
    for (int j = 0; j < 8; ++j) a[j] += w * bf2f(u[j]);
  }
  if (half == 1) {
    #pragma unroll
    for (int j = 0; j < 8; ++j) red[cb8][j] = a[j];
  }
  __syncthreads();
  if (half == 0) {
    #pragma unroll
    for (int j = 0; j < 8; ++j) out[cb8 * 8 + j] = a[j] + red[cb8][j];
  }
}

__global__ void ctx_red4_k(const float* __restrict__ cp, float* __restrict__ out) {
  int t = blockIdx.x * 256 + threadIdx.x;   // 32768
  int b = t >> 10, e = t & 1023;
  float a = 0.f;
  #pragma unroll
  for (int mt = 0; mt < 16; ++mt) a += cp[(((size_t)(b * 16 + mt)) << 10) + e];
  out[t] = a;
}

extern "C" void kernel_launch(void* const* d_in, const int* in_sizes, int n_in,
                              void* d_out, int out_size, void* d_ws, size_t ws_size,
                              hipStream_t stream) {
  const float* dec  = (const float*)d_in[0];
  const float* enc  = (const float*)d_in[1];
  const int*   mask = (const int*)d_in[2];
  const float* Wenc = (const float*)d_in[3];
  const float* Wdec = (const float*)d_in[4];
  const float* v    = (const float*)d_in[5];
  float* out_ctx = (float*)d_out;                 // [32][1024]
  float* out_w   = (float*)d_out + 32768;         // [32][2048]

  char* ws = (char*)d_ws;
  unsigned short* Wt = (unsigned short*)ws;                       // 2 MB  bf16 W_enc swizzled tiles
  float* dh    = (float*)(ws + (2u << 20));                       // 128 KB
  int*   rows  = (int*)(ws + (2u << 20) + (128u << 10));          // 256 KB
  float* wc    = (float*)(ws + (2u << 20) + (384u << 10));        // 256 KB
  int*   cnt   = (int*)(ws + (2u << 20) + (640u << 10));          // 4 KB
  float* pscores = (float*)(ws + (3u << 20));                     // 2 MB  [8][32][2048]
  float* cp      = (float*)(ws + (5u << 20));                     // 2 MB  [32][16][1024]
  unsigned short* encP = (unsigned short*)(ws + (8ull << 20));    // 128 MB packed swizzled enc tiles

  hipLaunchKernelGGL(prep_w4_k,  dim3(512),  dim3(256), 0, stream, Wenc, Wt);
  hipLaunchKernelGGL(prep_dh_k,  dim3(128),  dim3(256), 0, stream, dec, Wdec, dh);
  hipLaunchKernelGGL(compact_k,  dim3(32),   dim3(256), 0, stream, mask, rows, cnt, out_w);
  hipLaunchKernelGGL(pack4_k,    dim3(512),  dim3(256), 0, stream, enc, rows, cnt, encP);
  hipLaunchKernelGGL(score4_k,   dim3(4096), dim3(256), 0, stream, encP, Wt, dh, v, cnt, pscores);
  hipLaunchKernelGGL(softmax4_k, dim3(32),   dim3(256), 0, stream, pscores, rows, cnt, out_w, wc);
  hipLaunchKernelGGL(ctx4_k,     dim3(512),  dim3(256), 0, stream, encP, wc, cnt, cp);
  hipLaunchKernelGGL(ctx_red4_k, dim3(128),  dim3(256), 0, stream, cp, out_ctx);
}